// Round 1
// baseline (246.632 us; speedup 1.0000x reference)
//
#include <hip/hip_runtime.h>

#define DIM 256
#define HALF 128
#define N_EDGES_CONST 400000

// 32 lanes per edge; each lane loads float4 (16B) from each of the 6
// quarter-rows (h_real, h_imag, t_real, t_imag, r_real, r_imag).
// 32 lanes x 16B = 512B contiguous per half-row -> perfectly coalesced.
__global__ __launch_bounds__(256) void complex_score_kernel(
    const float* __restrict__ node_emb,
    const float* __restrict__ rel_emb,
    const int* __restrict__ src,
    const int* __restrict__ dst,
    const int* __restrict__ rel_id,
    float* __restrict__ out,
    int n_edges)
{
    const int tid  = blockIdx.x * blockDim.x + threadIdx.x;
    const int edge = tid >> 5;          // 32 lanes per edge
    const int lane = tid & 31;
    if (edge >= n_edges) return;

    const int s = src[edge];
    const int d = dst[edge];
    const int r = rel_id[edge];

    const float4* __restrict__ hp = (const float4*)(node_emb + (size_t)s * DIM);
    const float4* __restrict__ tp = (const float4*)(node_emb + (size_t)d * DIM);
    const float4* __restrict__ rp = (const float4*)(rel_emb  + (size_t)r * DIM);

    // real half: elements [0,128) = float4 slots [0,32)
    // imag half: elements [128,256) = float4 slots [32,64)
    float4 rh = hp[lane];
    float4 ih = hp[lane + 32];
    float4 rt = tp[lane];
    float4 it = tp[lane + 32];
    float4 rr = rp[lane];
    float4 ir = rp[lane + 32];

    // score = rr*(rh*rt + ih*it) + ir*(rh*it - ih*rt)
    float acc;
    {
        float a0 = rr.x * (rh.x * rt.x + ih.x * it.x) + ir.x * (rh.x * it.x - ih.x * rt.x);
        float a1 = rr.y * (rh.y * rt.y + ih.y * it.y) + ir.y * (rh.y * it.y - ih.y * rt.y);
        float a2 = rr.z * (rh.z * rt.z + ih.z * it.z) + ir.z * (rh.z * it.z - ih.z * rt.z);
        float a3 = rr.w * (rh.w * rt.w + ih.w * it.w) + ir.w * (rh.w * it.w - ih.w * rt.w);
        acc = (a0 + a1) + (a2 + a3);
    }

    // reduce across the 32-lane group
    #pragma unroll
    for (int off = 16; off > 0; off >>= 1)
        acc += __shfl_xor(acc, off, 32);

    if (lane == 0)
        out[edge] = acc;
}

extern "C" void kernel_launch(void* const* d_in, const int* in_sizes, int n_in,
                              void* d_out, int out_size, void* d_ws, size_t ws_size,
                              hipStream_t stream) {
    const float* node_emb = (const float*)d_in[0];
    const float* rel_emb  = (const float*)d_in[1];
    const int*   src      = (const int*)d_in[2];
    const int*   dst      = (const int*)d_in[3];
    const int*   rel_id   = (const int*)d_in[4];
    float* out = (float*)d_out;

    const int n_edges = in_sizes[2];           // 400000
    const int threads_per_block = 256;
    const long long total_threads = (long long)n_edges * 32;
    const int blocks = (int)((total_threads + threads_per_block - 1) / threads_per_block);

    complex_score_kernel<<<blocks, threads_per_block, 0, stream>>>(
        node_emb, rel_emb, src, dst, rel_id, out, n_edges);
}

// Round 3
// 225.971 us; speedup vs baseline: 1.0914x; 1.0914x over previous
//
#include <hip/hip_runtime.h>
#include <hip/hip_fp16.h>
#include <string.h>

#define DIM 256

// ---------- fp32 -> fp16 compression (runs every launch; ws is re-poisoned) ----
// Each thread converts 8 floats (two float4 loads) -> one int4 (8 halves) store.
__global__ __launch_bounds__(256) void f32_to_f16_kernel(
    const float* __restrict__ in, int4* __restrict__ out, int n8)
{
    int i = blockIdx.x * blockDim.x + threadIdx.x;
    if (i >= n8) return;
    const float4* p = (const float4*)in + 2 * (size_t)i;
    float4 a = p[0];
    float4 b = p[1];
    __half2 h0 = __float22half2_rn(make_float2(a.x, a.y));
    __half2 h1 = __float22half2_rn(make_float2(a.z, a.w));
    __half2 h2 = __float22half2_rn(make_float2(b.x, b.y));
    __half2 h3 = __float22half2_rn(make_float2(b.z, b.w));
    int4 o;
    memcpy(&o.x, &h0, 4);
    memcpy(&o.y, &h1, 4);
    memcpy(&o.z, &h2, 4);
    memcpy(&o.w, &h3, 4);
    out[i] = o;
}

// ---------- main gather/score kernel on fp16 rows ------------------------------
// 32 lanes per edge. A fp16 row is 512B = 32 lanes x int4 -> ONE dwordx4 per row.
// Lane l holds elements [8l, 8l+8): lanes 0-15 real half, lanes 16-31 imag half.
// Pair element k with k+128 via __shfl_xor(16).
//   lane<16 : partial = sum rr * (rh*rt + ih*it)
//   lane>=16: partial = sum ir * (rh*it - ih*rt)
// Sum of all 32 lane-partials = score.
__global__ __launch_bounds__(256) void complex_score_f16_kernel(
    const __half* __restrict__ node,
    const __half* __restrict__ rel,
    const int* __restrict__ src,
    const int* __restrict__ dst,
    const int* __restrict__ rid,
    float* __restrict__ out,
    int n_edges)
{
    const int tid  = blockIdx.x * blockDim.x + threadIdx.x;
    const int edge = tid >> 5;
    const int lane = tid & 31;
    if (edge >= n_edges) return;

    const int s = src[edge];
    const int d = dst[edge];
    const int r = rid[edge];

    const int4* hp = (const int4*)(node + (size_t)s * DIM);
    const int4* tp = (const int4*)(node + (size_t)d * DIM);
    const int4* rp = (const int4*)(rel  + (size_t)r * DIM);

    int4 hv = hp[lane];
    int4 tv = tp[lane];
    int4 rv = rp[lane];

    // exchange h and t with the partner lane (lane ^ 16); r uses own half only
    int4 hq, tq;
    hq.x = __shfl_xor(hv.x, 16); hq.y = __shfl_xor(hv.y, 16);
    hq.z = __shfl_xor(hv.z, 16); hq.w = __shfl_xor(hv.w, 16);
    tq.x = __shfl_xor(tv.x, 16); tq.y = __shfl_xor(tv.y, 16);
    tq.z = __shfl_xor(tv.z, 16); tq.w = __shfl_xor(tv.w, 16);

    const bool hi = (lane & 16) != 0;
    float acc = 0.0f;

    #define UP(v, f2) { __half2 _h; memcpy(&_h, &(v), 4); f2 = __half22float2(_h); }
    #define TERM(c) { \
        float2 oh, ph, ot, pt, rr; \
        UP(hv.c, oh); UP(hq.c, ph); \
        UP(tv.c, ot); UP(tq.c, pt); \
        UP(rv.c, rr); \
        float tx = hi ? (ph.x * ot.x - oh.x * pt.x) : (oh.x * ot.x + ph.x * pt.x); \
        float ty = hi ? (ph.y * ot.y - oh.y * pt.y) : (oh.y * ot.y + ph.y * pt.y); \
        acc = fmaf(rr.x, tx, acc); \
        acc = fmaf(rr.y, ty, acc); }

    TERM(x) TERM(y) TERM(z) TERM(w)
    #undef TERM
    #undef UP

    // reduce across the 32-lane group
    #pragma unroll
    for (int off = 16; off > 0; off >>= 1)
        acc += __shfl_xor(acc, off);

    if (lane == 0)
        out[edge] = acc;
}

// ---------- fallback: direct fp32 path (if ws is too small) --------------------
__global__ __launch_bounds__(256) void complex_score_f32_kernel(
    const float* __restrict__ node_emb,
    const float* __restrict__ rel_emb,
    const int* __restrict__ src,
    const int* __restrict__ dst,
    const int* __restrict__ rel_id,
    float* __restrict__ out,
    int n_edges)
{
    const int tid  = blockIdx.x * blockDim.x + threadIdx.x;
    const int edge = tid >> 5;
    const int lane = tid & 31;
    if (edge >= n_edges) return;

    const int s = src[edge];
    const int d = dst[edge];
    const int r = rel_id[edge];

    const float4* hp = (const float4*)(node_emb + (size_t)s * DIM);
    const float4* tp = (const float4*)(node_emb + (size_t)d * DIM);
    const float4* rp = (const float4*)(rel_emb  + (size_t)r * DIM);

    float4 rh = hp[lane];
    float4 ih = hp[lane + 32];
    float4 rt = tp[lane];
    float4 it = tp[lane + 32];
    float4 rr = rp[lane];
    float4 ir = rp[lane + 32];

    float a0 = rr.x * (rh.x * rt.x + ih.x * it.x) + ir.x * (rh.x * it.x - ih.x * rt.x);
    float a1 = rr.y * (rh.y * rt.y + ih.y * it.y) + ir.y * (rh.y * it.y - ih.y * rt.y);
    float a2 = rr.z * (rh.z * rt.z + ih.z * it.z) + ir.z * (rh.z * it.z - ih.z * rt.z);
    float a3 = rr.w * (rh.w * rt.w + ih.w * it.w) + ir.w * (rh.w * it.w - ih.w * rt.w);
    float acc = (a0 + a1) + (a2 + a3);

    #pragma unroll
    for (int off = 16; off > 0; off >>= 1)
        acc += __shfl_xor(acc, off, 32);

    if (lane == 0)
        out[edge] = acc;
}

extern "C" void kernel_launch(void* const* d_in, const int* in_sizes, int n_in,
                              void* d_out, int out_size, void* d_ws, size_t ws_size,
                              hipStream_t stream) {
    const float* node_emb = (const float*)d_in[0];
    const float* rel_emb  = (const float*)d_in[1];
    const int*   src      = (const int*)d_in[2];
    const int*   dst      = (const int*)d_in[3];
    const int*   rel_id   = (const int*)d_in[4];
    float* out = (float*)d_out;

    const int n_edges = in_sizes[2];            // 400000
    const int n_nodes = in_sizes[0] / DIM;      // 100000
    const int n_rels  = in_sizes[1] / DIM;      // 1000

    const size_t f16_bytes = ((size_t)n_nodes + (size_t)n_rels) * DIM * 2;

    const int tpb = 256;
    const long long total_threads = (long long)n_edges * 32;
    const int score_blocks = (int)((total_threads + tpb - 1) / tpb);

    if (ws_size >= f16_bytes) {
        __half* node_f16 = (__half*)d_ws;
        __half* rel_f16  = node_f16 + (size_t)n_nodes * DIM;

        const int n8_node = n_nodes * DIM / 8;  // 3,200,000
        const int n8_rel  = n_rels  * DIM / 8;  // 32,000

        f32_to_f16_kernel<<<(n8_node + tpb - 1) / tpb, tpb, 0, stream>>>(
            node_emb, (int4*)node_f16, n8_node);
        f32_to_f16_kernel<<<(n8_rel + tpb - 1) / tpb, tpb, 0, stream>>>(
            rel_emb, (int4*)rel_f16, n8_rel);

        complex_score_f16_kernel<<<score_blocks, tpb, 0, stream>>>(
            node_f16, rel_f16, src, dst, rel_id, out, n_edges);
    } else {
        complex_score_f32_kernel<<<score_blocks, tpb, 0, stream>>>(
            node_emb, rel_emb, src, dst, rel_id, out, n_edges);
    }
}